// Round 2
// baseline (445.043 us; speedup 1.0000x reference)
//
#include <hip/hip_runtime.h>
#include <cstdint>

static constexpr int B_DIM = 256;
static constexpr int N_DIM = 65536;
static constexpr int BN = B_DIM * N_DIM;      // 16,777,216 elements per array
static constexpr int VEC = BN / 4;            // float4 count = 4,194,304
static constexpr int ROW0_VEC = N_DIM / 4;    // 16,384 float4s in row 0
static constexpr int TPB = 256;
static constexpr int NROW0_BLK = ROW0_VEC / TPB;  // 64 blocks cover row 0

// Native clang vector type — required by __builtin_nontemporal_load/store
// (HIP_vector_type<float,4> is a struct and is rejected). Same 16-B layout.
typedef float floatx4 __attribute__((ext_vector_type(4)));

// Fused AdEx-LIF step + winner-take-all lateral inhibition.
// Main elementwise pass writes z, v_new, i_new, w_new (nontemporal — streamed,
// never re-read). Row-0 blocks (bid < 64) reduce the WTA key (max v_before
// among spiked, first-index tiebreak) via wave shuffle + one atomicMax per
// wave, then use a device-scope-fenced ticket: the last row-0 block to finish
// applies the inhibition, eliminating the second kernel launch.
//
// Cross-XCD safety (G16): each row-0 block issues __threadfence() (device
// scope) BEFORE its ticket atomicAdd, so all its v/w/z stores and atomicMax
// are globally visible before the inhibitor (ticket==63) starts overwriting
// row 0. The inhibitor issues an acquire __threadfence() after winning the
// ticket, so its reads (winner's values) and WAW overwrites are ordered.
__global__ __launch_bounds__(TPB) void lif_fused(
    const floatx4* __restrict__ x, const floatx4* __restrict__ v,
    const floatx4* __restrict__ cur, const floatx4* __restrict__ w,
    floatx4* __restrict__ z_out, floatx4* __restrict__ v_out,
    floatx4* __restrict__ i_out, floatx4* __restrict__ w_out,
    unsigned long long* __restrict__ ws_key,
    unsigned int* __restrict__ ws_cnt)
{
    const int tid = threadIdx.x;
    const int bid = blockIdx.x;
    const int t = bid * TPB + tid;

    const floatx4 xv = __builtin_nontemporal_load(&x[t]);
    const floatx4 vv = __builtin_nontemporal_load(&v[t]);
    const floatx4 iv = __builtin_nontemporal_load(&cur[t]);
    const floatx4 wv = __builtin_nontemporal_load(&w[t]);

    floatx4 zo, vo, io, wo;

    const bool row0 = (bid < NROW0_BLK);   // block-uniform
    unsigned long long key = 0ull;

    #pragma unroll
    for (int k = 0; k < 4; ++k) {
        const float X = xv[k];
        const float V = vv[k];
        const float I = iv[k];
        const float W = wv[k];

        const float i_new = I + 0.5f * (X - I);
        const float e     = expf(V - 1.0f);            // DELTA_T=1, V_TH=1
        float v_new       = V + 0.5f * (-V + e + i_new - W);
        const float w_new = 0.5f * W;                  // A=0, tau_adapt_inv=0.5

        const bool spike  = (v_new >= 30.0f);
        const float v_before = v_new;
        if (spike) v_new = 0.0f;                       // V_RESET=0

        zo[k] = spike ? 1.0f : 0.0f;
        vo[k] = v_new;
        io[k] = i_new;
        wo[k] = w_new;                                 // B_PARAM=0 -> unchanged

        if (row0 && spike) {
            // positive float bits are order-preserving; ~idx -> ties pick min idx
            const unsigned vb  = __float_as_uint(v_before);
            const unsigned idx = (unsigned)(t * 4 + k);
            const unsigned long long cand =
                ((unsigned long long)vb << 32) | (unsigned long long)(~idx);
            key = (cand > key) ? cand : key;
        }
    }

    __builtin_nontemporal_store(zo, &z_out[t]);
    __builtin_nontemporal_store(vo, &v_out[t]);
    __builtin_nontemporal_store(io, &i_out[t]);
    __builtin_nontemporal_store(wo, &w_out[t]);

    if (!row0) return;

    // ---- row-0 epilogue: key reduction + last-block inhibition ----
    #pragma unroll
    for (int off = 32; off > 0; off >>= 1) {
        const unsigned long long other = __shfl_down(key, off, 64);
        key = (other > key) ? other : key;
    }
    if ((tid & 63) == 0 && key != 0ull) {
        atomicMax(ws_key, key);
    }

    // Release: make this block's v/w/z stores and atomicMax globally visible
    // before the ticket increment.
    __threadfence();
    __syncthreads();

    __shared__ unsigned int ticket;
    if (tid == 0) ticket = atomicAdd(ws_cnt, 1u);
    __syncthreads();

    if (ticket == NROW0_BLK - 1) {
        // Acquire: ensure we observe other blocks' row-0 stores and keys.
        __threadfence();

        __shared__ unsigned long long skey;
        if (tid == 0) skey = atomicMax(ws_key, 0ull);  // coherent read
        __syncthreads();
        const unsigned long long kk = skey;
        if (kk == 0ull) return;                        // no spike -> no inhibition

        const unsigned winner = ~(unsigned)(kk & 0xFFFFFFFFull);
        float* v0 = reinterpret_cast<float*>(v_out);
        float* w0 = reinterpret_cast<float*>(w_out);

        // Save winner's values before blasting (v is exactly V_RESET=0 since
        // the winner spiked, but read both for robustness).
        const float vwin = v0[winner];
        const float wwin = w0[winner];
        __syncthreads();                               // all reads done before blast

        const floatx4 m5 = {-5.0f, -5.0f, -5.0f, -5.0f};  // INHIBITION
        const floatx4 z4 = {0.0f, 0.0f, 0.0f, 0.0f};
        for (int i2 = tid; i2 < ROW0_VEC; i2 += TPB) {
            v_out[i2] = m5;
            w_out[i2] = z4;
        }
        __syncthreads();
        if (tid == 0) {
            v0[winner] = vwin;
            w0[winner] = wwin;
        }
    }
}

extern "C" void kernel_launch(void* const* d_in, const int* in_sizes, int n_in,
                              void* d_out, int out_size, void* d_ws, size_t ws_size,
                              hipStream_t stream) {
    const float* x   = (const float*)d_in[0];
    const float* v   = (const float*)d_in[1];
    const float* cur = (const float*)d_in[2];
    const float* w   = (const float*)d_in[3];
    float* out = (float*)d_out;

    float* z_out = out;
    float* v_out = out + (size_t)BN;
    float* i_out = out + 2ull * BN;
    float* w_out = out + 3ull * BN;

    unsigned long long* key = (unsigned long long*)d_ws;
    unsigned int* cnt = (unsigned int*)((char*)d_ws + 8);
    (void)hipMemsetAsync(d_ws, 0, 16, stream);  // zero key (8B) + ticket (4B)

    lif_fused<<<VEC / TPB, TPB, 0, stream>>>(
        (const floatx4*)x, (const floatx4*)v, (const floatx4*)cur, (const floatx4*)w,
        (floatx4*)z_out, (floatx4*)v_out, (floatx4*)i_out, (floatx4*)w_out, key, cnt);
}